// Round 6
// baseline (494.702 us; speedup 1.0000x reference)
//
#include <hip/hip_runtime.h>
#include <stdint.h>

#define B_   16
#define C_   512
#define H_   64
#define W_   64
#define NH_  8
#define HD_  64
#define HW_  4096

typedef __attribute__((ext_vector_type(8))) _Float16 f16x8;
typedef __attribute__((ext_vector_type(8))) unsigned short u16x8;
typedef __attribute__((ext_vector_type(4))) unsigned short u16x4;
typedef __attribute__((ext_vector_type(4))) float f32x4;

static __device__ __forceinline__ unsigned short f2h(float f) {
  _Float16 h = (_Float16)f;
  unsigned short u;
  __builtin_memcpy(&u, &h, 2);
  return u;
}

static __device__ __forceinline__ void gld_lds16(const void* g, void* l) {
  __builtin_amdgcn_global_load_lds((__attribute__((address_space(1))) void*)g,
                                   (__attribute__((address_space(3))) void*)l,
                                   16, 0, 0);
}

// ---------------- K0a: x (B,C,HW) fp32 -> xT (B,HW,C) f16 (transpose+convert)
__global__ __launch_bounds__(256) void rcca_tr(const float* __restrict__ x,
                                               unsigned short* __restrict__ xT) {
  __shared__ float lT[64 * 65];
  const int bid = blockIdx.x;
  const int st = bid & 63;          // hw tile
  const int ct = (bid >> 6) & 7;    // c tile
  const int b  = bid >> 9;
  const int t = threadIdx.x;
  const int hwl = t & 63;
  const int cl0 = (t >> 6) * 16;
  const float* src = x + ((size_t)(b * C_ + ct * 64 + cl0)) * HW_ + st * 64 + hwl;
#pragma unroll
  for (int jj = 0; jj < 16; ++jj)
    lT[(cl0 + jj) * 65 + hwl] = src[(size_t)jj * HW_];
  __syncthreads();
  const int hw2 = t >> 2;
  const int cc0 = (t & 3) * 16;
  u16x8 o0, o1;
#pragma unroll
  for (int u = 0; u < 8; ++u) {
    o0[u] = f2h(lT[(cc0 + u) * 65 + hw2]);
    o1[u] = f2h(lT[(cc0 + 8 + u) * 65 + hw2]);
  }
  unsigned short* dst = xT + ((size_t)b * HW_ + st * 64 + hw2) * C_ + ct * 64 + cc0;
  *(u16x8*)dst = o0;
  *(u16x8*)(dst + 8) = o1;
}

// ---------------- K0b: wq|wk|wv (512,512) fp32 -> Wc (1536,512) f16
__global__ __launch_bounds__(256) void rcca_cvtw(const float* __restrict__ wq,
                                                 const float* __restrict__ wk,
                                                 const float* __restrict__ wv,
                                                 unsigned short* __restrict__ Wc) {
  const int i = blockIdx.x * 256 + threadIdx.x;  // 196608 threads
  const int e = i * 4;
  const float* w = (e < 262144) ? wq : (e < 524288) ? wk : wv;
  const int off = e & 262143;
  const float4 v = *(const float4*)(w + off);
  u16x4 p;
  p[0] = f2h(v.x); p[1] = f2h(v.y); p[2] = f2h(v.z); p[3] = f2h(v.w);
  *(u16x4*)(Wc + e) = p;
}

// ---------------- K1: fused QKV projection + attention + residual, BK=32 double-buffer.
// Block = (b, head, ht): GEMM M=128 (2 h-rows x 64 w), N=192 (q|k|v of one head), K=512.
// Pipeline: prologue stages buf0; each of 16 iterations issues the NEXT 32-wide K-slab's
// gld_lds into the other buffer, runs 24 MFMAs on the current one, then ONE __syncthreads
// (the vmcnt drain lands after the compute phase). Per-buffer 20480 B, both buffers fit
// under the 73728 B attention footprint -> 2 blocks/CU (the r5 occupancy loss undone).
// Epilogue writes Q/K/V (+bias) to LDS, then per-row attention, then out = O + x.
// XCD swizzle: the 8 heads sharing one A-tile land on one XCD (xT read ~once per XCD).
__global__ __launch_bounds__(256) void rcca_fused(
    const unsigned short* __restrict__ xT, const unsigned short* __restrict__ Wc,
    const float* __restrict__ bq, const float* __restrict__ bk, const float* __restrict__ bv,
    const float* __restrict__ x, float* __restrict__ out) {
  __shared__ __align__(16) char smem[73728];
  // K-loop:  buf(p) at p*20480: lA [128][32] f16 swz [0,8192) | lB [192][32] f16 swz [8192,20480)
  // attn:    [hs*27648+0)      sQ[hs] [64][72] f16
  //          [hs*27648+9216)   sK[hs] [64][72] f16
  //          [hs*27648+18432)  sV[hs] [64][72] f16 (d-major)
  //          [55296+hs*9216)   sP[hs] [64][72] f16
  //          sO[hs] f32 [64][66] overlays sQ[hs]+sK[hs]
  const int sbid = blockIdx.x;
  const int lg = ((sbid & 7) << 9) | (sbid >> 3);  // bijective: 4096 % 8 == 0
  const int head = lg & 7;
  const int bh = lg >> 3;
  const int b = bh >> 5;
  const int ht = bh & 31;
  const int t = threadIdx.x;
  const int wid = t >> 6, lane = t & 63, r = lane & 15, q = lane >> 4;
  const int wm = wid >> 1, wn = wid & 1;  // wm = h-row (hs), wn = n-half (GEMM) / q-row-half (attn)
  const int wbase = wid * 1024;
  const unsigned short* Abase = xT + ((size_t)b * HW_ + ht * 128) * C_;
  f32x4 acc[4][6];
#pragma unroll
  for (int i = 0; i < 4; ++i)
#pragma unroll
    for (int j = 0; j < 6; ++j) acc[i][j] = (f32x4){0.f, 0.f, 0.f, 0.f};

  // stage one 32-wide K-slab into buf: LDS(row,ch) = global(row, ch^(row&3))
  auto stage = [&](char* buf, int k0) {
    char* lAb = buf;
    char* lBb = buf + 8192;
#pragma unroll
    for (int rr = 0; rr < 2; ++rr) {
      const int idx = rr * 256 + t;
      const int row = idx >> 2, ch = idx & 3;
      gld_lds16(Abase + (size_t)row * C_ + k0 + ((ch ^ (row & 3)) * 8),
                lAb + rr * 4096 + wbase);
    }
#pragma unroll
    for (int rr = 0; rr < 3; ++rr) {
      const int idx = rr * 256 + t;
      const int row = idx >> 2, ch = idx & 3;   // row = n (0..191)
      const int wrow = (row >> 6) * 512 + head * 64 + (row & 63);
      gld_lds16(Wc + (size_t)wrow * C_ + k0 + ((ch ^ (row & 3)) * 8),
                lBb + rr * 4096 + wbase);
    }
  };

  stage(smem, 0);
  __syncthreads();

  for (int tt = 0; tt < 16; ++tt) {
    char* cur = smem + (tt & 1) * 20480;
    if (tt < 15) stage(smem + ((tt & 1) ^ 1) * 20480, (tt + 1) * 32);
    const unsigned short* lA = (const unsigned short*)cur;
    const unsigned short* lB = (const unsigned short*)(cur + 8192);
    const int cb = q ^ (r & 3);
    f16x8 av[4], bw[6];
#pragma unroll
    for (int i = 0; i < 4; ++i)
      av[i] = *(const f16x8*)&lA[(wm * 64 + i * 16 + r) * 32 + cb * 8];
#pragma unroll
    for (int j = 0; j < 6; ++j)
      bw[j] = *(const f16x8*)&lB[(wn * 96 + j * 16 + r) * 32 + cb * 8];
#pragma unroll
    for (int i = 0; i < 4; ++i)
#pragma unroll
      for (int j = 0; j < 6; ++j)
        acc[i][j] = __builtin_amdgcn_mfma_f32_16x16x32_f16(av[i], bw[j], acc[i][j], 0, 0, 0);
    __syncthreads();  // stage(t+1) drained after compute; all MFMA(t) LDS reads complete
  }
  // ---- epilogue: acc -> sQ/sK/sV of row hs=wm, bias fused.
  // C layout: m = wm*64 + i*16 + q*4 + reg (w = m&63); n = wn*96 + j*16 + r.
  unsigned short* sQh = (unsigned short*)(smem + wm * 27648);
  unsigned short* sKh = (unsigned short*)(smem + wm * 27648 + 9216);
  unsigned short* sVh = (unsigned short*)(smem + wm * 27648 + 18432);
#pragma unroll
  for (int j = 0; j < 6; ++j) {
    const int n0 = wn * 96 + j * 16;
    const int sel = n0 >> 6;          // 0=q 1=k 2=v (16-aligned frags never straddle)
    const int dd = (n0 & 63) + r;
    const float* bias = (sel == 0) ? bq : (sel == 1) ? bk : bv;
    const float bias_v = bias[head * 64 + dd];
    if (sel < 2) {
      unsigned short* dst = (sel == 0) ? sQh : sKh;
#pragma unroll
      for (int i = 0; i < 4; ++i)
#pragma unroll
        for (int reg = 0; reg < 4; ++reg)
          dst[(i * 16 + q * 4 + reg) * 72 + dd] = f2h(acc[i][j][reg] + bias_v);
    } else {
#pragma unroll
      for (int i = 0; i < 4; ++i) {
        u16x4 pk;
#pragma unroll
        for (int reg = 0; reg < 4; ++reg) pk[reg] = f2h(acc[i][j][reg] + bias_v);
        *(u16x4*)&sVh[dd * 72 + i * 16 + q * 4] = pk;  // sV is [d][w]
      }
    }
  }
  __syncthreads();
  // ---- attention: wave (wm=hs, wn=q-row half). S = Q K^T, softmax, O = P V.
  unsigned short* sPh = (unsigned short*)(smem + 55296 + wm * 9216);
  f32x4 s2[2][4];
#pragma unroll
  for (int i2 = 0; i2 < 2; ++i2)
#pragma unroll
    for (int j = 0; j < 4; ++j) s2[i2][j] = (f32x4){0.f, 0.f, 0.f, 0.f};
#pragma unroll
  for (int kk = 0; kk < 64; kk += 32) {
    f16x8 aq0 = *(const f16x8*)&sQh[(wn * 32 + r) * 72 + kk + q * 8];
    f16x8 aq1 = *(const f16x8*)&sQh[(wn * 32 + 16 + r) * 72 + kk + q * 8];
#pragma unroll
    for (int j = 0; j < 4; ++j) {
      f16x8 bk8 = *(const f16x8*)&sKh[(j * 16 + r) * 72 + kk + q * 8];
      s2[0][j] = __builtin_amdgcn_mfma_f32_16x16x32_f16(aq0, bk8, s2[0][j], 0, 0, 0);
      s2[1][j] = __builtin_amdgcn_mfma_f32_16x16x32_f16(aq1, bk8, s2[1][j], 0, 0, 0);
    }
  }
  // softmax over w' (no scale in reference); lane holds S[row][col=j*16+r]
  float inv2[2][4];
#pragma unroll
  for (int i2 = 0; i2 < 2; ++i2)
#pragma unroll
    for (int reg = 0; reg < 4; ++reg) {
      float mx = fmaxf(fmaxf(s2[i2][0][reg], s2[i2][1][reg]),
                       fmaxf(s2[i2][2][reg], s2[i2][3][reg]));
#pragma unroll
      for (int o = 1; o < 16; o <<= 1) mx = fmaxf(mx, __shfl_xor(mx, o, 64));
      float p0 = __expf(s2[i2][0][reg] - mx);
      float p1 = __expf(s2[i2][1][reg] - mx);
      float p2 = __expf(s2[i2][2][reg] - mx);
      float p3 = __expf(s2[i2][3][reg] - mx);
      float sum = p0 + p1 + p2 + p3;
#pragma unroll
      for (int o = 1; o < 16; o <<= 1) sum += __shfl_xor(sum, o, 64);
      inv2[i2][reg] = 1.0f / sum;
      const int row = wn * 32 + i2 * 16 + q * 4 + reg;
      sPh[row * 72 + r] = f2h(p0);
      sPh[row * 72 + 16 + r] = f2h(p1);
      sPh[row * 72 + 32 + r] = f2h(p2);
      sPh[row * 72 + 48 + r] = f2h(p3);
    }
  __syncthreads();  // QK reads done before sO overlays sQ/sK; sP visible
  f32x4 o4[2][4];
#pragma unroll
  for (int i2 = 0; i2 < 2; ++i2)
#pragma unroll
    for (int jd = 0; jd < 4; ++jd) o4[i2][jd] = (f32x4){0.f, 0.f, 0.f, 0.f};
#pragma unroll
  for (int kk = 0; kk < 64; kk += 32) {
    f16x8 ap0 = *(const f16x8*)&sPh[(wn * 32 + r) * 72 + kk + q * 8];
    f16x8 ap1 = *(const f16x8*)&sPh[(wn * 32 + 16 + r) * 72 + kk + q * 8];
#pragma unroll
    for (int jd = 0; jd < 4; ++jd) {
      f16x8 bv8 = *(const f16x8*)&sVh[(jd * 16 + r) * 72 + kk + q * 8];
      o4[0][jd] = __builtin_amdgcn_mfma_f32_16x16x32_f16(ap0, bv8, o4[0][jd], 0, 0, 0);
      o4[1][jd] = __builtin_amdgcn_mfma_f32_16x16x32_f16(ap1, bv8, o4[1][jd], 0, 0, 0);
    }
  }
  float* sOh = (float*)(smem + wm * 27648);  // [64 d][66 w], overlays sQ[hs]+sK[hs]
#pragma unroll
  for (int i2 = 0; i2 < 2; ++i2)
#pragma unroll
    for (int jd = 0; jd < 4; ++jd) {
      const int d = jd * 16 + r;
#pragma unroll
      for (int reg = 0; reg < 4; ++reg) {
        const int w = wn * 32 + i2 * 16 + q * 4 + reg;
        sOh[d * 66 + w] = o4[i2][jd][reg] * inv2[i2][reg];
      }
    }
  __syncthreads();
  // out[b][head*64+d][h][w] = O[w][d] + x; coalesced float4 along w, both h-rows
  const int d = t >> 2, w0 = (t & 3) * 16;
#pragma unroll
  for (int hs = 0; hs < 2; ++hs) {
    const float* sO2 = (const float*)(smem + hs * 27648);
    const int h = ht * 2 + hs;
    const size_t obase = (((size_t)b * C_ + head * 64 + d) * H_ + h) * (size_t)W_ + w0;
    const float4* xr = (const float4*)(x + obase);
    float4* op = (float4*)(out + obase);
#pragma unroll
    for (int u = 0; u < 4; ++u) {
      float4 xv = xr[u];
      float4 ov;
      ov.x = sO2[d * 66 + w0 + u * 4 + 0] + xv.x;
      ov.y = sO2[d * 66 + w0 + u * 4 + 1] + xv.y;
      ov.z = sO2[d * 66 + w0 + u * 4 + 2] + xv.z;
      ov.w = sO2[d * 66 + w0 + u * 4 + 3] + xv.w;
      op[u] = ov;
    }
  }
}

extern "C" void kernel_launch(void* const* d_in, const int* in_sizes, int n_in,
                              void* d_out, int out_size, void* d_ws, size_t ws_size,
                              hipStream_t stream) {
  const float* x  = (const float*)d_in[0];
  const float* wq = (const float*)d_in[1];
  const float* bq = (const float*)d_in[2];
  const float* wk = (const float*)d_in[3];
  const float* bk = (const float*)d_in[4];
  const float* wv = (const float*)d_in[5];
  const float* bv = (const float*)d_in[6];
  float* out = (float*)d_out;
  char* ws = (char*)d_ws;
  // ws layout: xT 64 MiB | Wc 1.5 MiB
  unsigned short* xT = (unsigned short*)ws;
  unsigned short* Wc = (unsigned short*)(ws + (size_t)67108864);
  hipLaunchKernelGGL(rcca_tr,    dim3(8192), dim3(256), 0, stream, x, xT);
  hipLaunchKernelGGL(rcca_cvtw,  dim3(768),  dim3(256), 0, stream, wq, wk, wv, Wc);
  hipLaunchKernelGGL(rcca_fused, dim3(4096), dim3(256), 0, stream, xT, Wc, bq, bk, bv, x, out);
}

// Round 7
// 409.170 us; speedup vs baseline: 1.2090x; 1.2090x over previous
//
#include <hip/hip_runtime.h>
#include <stdint.h>

#define B_   16
#define C_   512
#define H_   64
#define W_   64
#define NH_  8
#define HD_  64
#define HW_  4096

typedef __attribute__((ext_vector_type(8))) _Float16 f16x8;
typedef __attribute__((ext_vector_type(8))) unsigned short u16x8;
typedef __attribute__((ext_vector_type(4))) unsigned short u16x4;
typedef __attribute__((ext_vector_type(4))) float f32x4;

static __device__ __forceinline__ unsigned short f2h(float f) {
  _Float16 h = (_Float16)f;
  unsigned short u;
  __builtin_memcpy(&u, &h, 2);
  return u;
}

static __device__ __forceinline__ void gld_lds16(const void* g, void* l) {
  __builtin_amdgcn_global_load_lds((__attribute__((address_space(1))) void*)g,
                                   (__attribute__((address_space(3))) void*)l,
                                   16, 0, 0);
}

// ---------------- K0a: x (B,C,HW) fp32 -> xT (B,HW,C) f16 (transpose+convert)
__global__ __launch_bounds__(256) void rcca_tr(const float* __restrict__ x,
                                               unsigned short* __restrict__ xT) {
  __shared__ float lT[64 * 65];
  const int bid = blockIdx.x;
  const int st = bid & 63;          // hw tile
  const int ct = (bid >> 6) & 7;    // c tile
  const int b  = bid >> 9;
  const int t = threadIdx.x;
  const int hwl = t & 63;
  const int cl0 = (t >> 6) * 16;
  const float* src = x + ((size_t)(b * C_ + ct * 64 + cl0)) * HW_ + st * 64 + hwl;
#pragma unroll
  for (int jj = 0; jj < 16; ++jj)
    lT[(cl0 + jj) * 65 + hwl] = src[(size_t)jj * HW_];
  __syncthreads();
  const int hw2 = t >> 2;
  const int cc0 = (t & 3) * 16;
  u16x8 o0, o1;
#pragma unroll
  for (int u = 0; u < 8; ++u) {
    o0[u] = f2h(lT[(cc0 + u) * 65 + hw2]);
    o1[u] = f2h(lT[(cc0 + 8 + u) * 65 + hw2]);
  }
  unsigned short* dst = xT + ((size_t)b * HW_ + st * 64 + hw2) * C_ + ct * 64 + cc0;
  *(u16x8*)dst = o0;
  *(u16x8*)(dst + 8) = o1;
}

// ---------------- K0b: wq|wk|wv (512,512) fp32 -> Wc (1536,512) f16
__global__ __launch_bounds__(256) void rcca_cvtw(const float* __restrict__ wq,
                                                 const float* __restrict__ wk,
                                                 const float* __restrict__ wv,
                                                 unsigned short* __restrict__ Wc) {
  const int i = blockIdx.x * 256 + threadIdx.x;  // 196608 threads
  const int e = i * 4;
  const float* w = (e < 262144) ? wq : (e < 524288) ? wk : wv;
  const int off = e & 262143;
  const float4 v = *(const float4*)(w + off);
  u16x4 p;
  p[0] = f2h(v.x); p[1] = f2h(v.y); p[2] = f2h(v.z); p[3] = f2h(v.w);
  *(u16x4*)(Wc + e) = p;
}

// ---------------- K1: fused QKV projection + attention + residual.
// BK=32, 3-deep ring buffer, counted vmcnt (T3+T4): per iter issue stage(t+2), wait
// vmcnt(10) (only stage(t) must have landed; 10 loads from stages t+1/t+2 stay in
// flight ACROSS the barrier), raw s_barrier, 24 MFMAs (setprio-wrapped), s_barrier.
// Ring: stage(t+2) writes buf[(t+2)%3]; its previous readers (MFMA(t-1)) passed their
// closing barrier before the issue. 3x20480 = 61440 B fits under the 73728 B attn
// footprint -> LDS allocation unchanged. Epilogue peels t=14 (vmcnt 5), t=15 (vmcnt 0).
// XCD swizzle: the 8 heads sharing one A-tile land on one XCD (xT read ~once per XCD).
__global__ __launch_bounds__(256) void rcca_fused(
    const unsigned short* __restrict__ xT, const unsigned short* __restrict__ Wc,
    const float* __restrict__ bq, const float* __restrict__ bk, const float* __restrict__ bv,
    const float* __restrict__ x, float* __restrict__ out) {
  __shared__ __align__(16) char smem[73728];
  // K-loop:  buf(p) at p*20480, p=0..2: lA [128][32] f16 swz | lB [192][32] f16 swz
  // attn:    [hs*27648+0)      sQ[hs] [64][72] f16
  //          [hs*27648+9216)   sK[hs] [64][72] f16
  //          [hs*27648+18432)  sV[hs] [64][72] f16 (d-major)
  //          [55296+hs*9216)   sP[hs] [64][72] f16
  //          sO[hs] f32 [64][66] overlays sQ[hs]+sK[hs]
  const int sbid = blockIdx.x;
  const int lg = ((sbid & 7) << 9) | (sbid >> 3);  // bijective: 4096 % 8 == 0
  const int head = lg & 7;
  const int bh = lg >> 3;
  const int b = bh >> 5;
  const int ht = bh & 31;
  const int t = threadIdx.x;
  const int wid = t >> 6, lane = t & 63, r = lane & 15, q = lane >> 4;
  const int wm = wid >> 1, wn = wid & 1;  // wm = h-row (hs), wn = n-half (GEMM) / q-row-half (attn)
  const int wbase = wid * 1024;
  const unsigned short* Abase = xT + ((size_t)b * HW_ + ht * 128) * C_;
  f32x4 acc[4][6];
#pragma unroll
  for (int i = 0; i < 4; ++i)
#pragma unroll
    for (int j = 0; j < 6; ++j) acc[i][j] = (f32x4){0.f, 0.f, 0.f, 0.f};

  // stage one 32-wide K-slab into buf: LDS(row,ch) = global(row, ch^(row&3))
  auto stage = [&](char* buf, int k0) {
    char* lAb = buf;
    char* lBb = buf + 8192;
#pragma unroll
    for (int rr = 0; rr < 2; ++rr) {
      const int idx = rr * 256 + t;
      const int row = idx >> 2, ch = idx & 3;
      gld_lds16(Abase + (size_t)row * C_ + k0 + ((ch ^ (row & 3)) * 8),
                lAb + rr * 4096 + wbase);
    }
#pragma unroll
    for (int rr = 0; rr < 3; ++rr) {
      const int idx = rr * 256 + t;
      const int row = idx >> 2, ch = idx & 3;   // row = n (0..191)
      const int wrow = (row >> 6) * 512 + head * 64 + (row & 63);
      gld_lds16(Wc + (size_t)wrow * C_ + k0 + ((ch ^ (row & 3)) * 8),
                lBb + rr * 4096 + wbase);
    }
  };

  // prologue: two slabs in flight
  stage(smem, 0);
  stage(smem + 20480, 32);

#pragma unroll
  for (int tt = 0; tt < 16; ++tt) {
    if (tt < 14) stage(smem + ((tt + 2) % 3) * 20480, (tt + 2) * 32);
    if (tt < 14)      asm volatile("s_waitcnt vmcnt(10)" ::: "memory");
    else if (tt == 14) asm volatile("s_waitcnt vmcnt(5)" ::: "memory");
    else               asm volatile("s_waitcnt vmcnt(0)" ::: "memory");
    __builtin_amdgcn_s_barrier();   // buf[tt%3] fully staged in all waves
    const unsigned short* lA = (const unsigned short*)(smem + (tt % 3) * 20480);
    const unsigned short* lB = (const unsigned short*)(smem + (tt % 3) * 20480 + 8192);
    const int cb = q ^ (r & 3);
    f16x8 av[4], bw[6];
#pragma unroll
    for (int i = 0; i < 4; ++i)
      av[i] = *(const f16x8*)&lA[(wm * 64 + i * 16 + r) * 32 + cb * 8];
#pragma unroll
    for (int j = 0; j < 6; ++j)
      bw[j] = *(const f16x8*)&lB[(wn * 96 + j * 16 + r) * 32 + cb * 8];
    __builtin_amdgcn_s_setprio(1);
#pragma unroll
    for (int i = 0; i < 4; ++i)
#pragma unroll
      for (int j = 0; j < 6; ++j)
        acc[i][j] = __builtin_amdgcn_mfma_f32_16x16x32_f16(av[i], bw[j], acc[i][j], 0, 0, 0);
    __builtin_amdgcn_s_setprio(0);
    __builtin_amdgcn_s_barrier();   // all reads of buf[tt%3] done before it is re-staged
  }
  // ---- epilogue: acc -> sQ/sK/sV of row hs=wm, bias fused.
  // C layout: m = wm*64 + i*16 + q*4 + reg (w = m&63); n = wn*96 + j*16 + r.
  unsigned short* sQh = (unsigned short*)(smem + wm * 27648);
  unsigned short* sKh = (unsigned short*)(smem + wm * 27648 + 9216);
  unsigned short* sVh = (unsigned short*)(smem + wm * 27648 + 18432);
#pragma unroll
  for (int j = 0; j < 6; ++j) {
    const int n0 = wn * 96 + j * 16;
    const int sel = n0 >> 6;          // 0=q 1=k 2=v (16-aligned frags never straddle)
    const int dd = (n0 & 63) + r;
    const float* bias = (sel == 0) ? bq : (sel == 1) ? bk : bv;
    const float bias_v = bias[head * 64 + dd];
    if (sel < 2) {
      unsigned short* dst = (sel == 0) ? sQh : sKh;
#pragma unroll
      for (int i = 0; i < 4; ++i)
#pragma unroll
        for (int reg = 0; reg < 4; ++reg)
          dst[(i * 16 + q * 4 + reg) * 72 + dd] = f2h(acc[i][j][reg] + bias_v);
    } else {
#pragma unroll
      for (int i = 0; i < 4; ++i) {
        u16x4 pk;
#pragma unroll
        for (int reg = 0; reg < 4; ++reg) pk[reg] = f2h(acc[i][j][reg] + bias_v);
        *(u16x4*)&sVh[dd * 72 + i * 16 + q * 4] = pk;  // sV is [d][w]
      }
    }
  }
  __syncthreads();
  // ---- attention: wave (wm=hs, wn=q-row half). S = Q K^T, softmax, O = P V.
  unsigned short* sPh = (unsigned short*)(smem + 55296 + wm * 9216);
  f32x4 s2[2][4];
#pragma unroll
  for (int i2 = 0; i2 < 2; ++i2)
#pragma unroll
    for (int j = 0; j < 4; ++j) s2[i2][j] = (f32x4){0.f, 0.f, 0.f, 0.f};
#pragma unroll
  for (int kk = 0; kk < 64; kk += 32) {
    f16x8 aq0 = *(const f16x8*)&sQh[(wn * 32 + r) * 72 + kk + q * 8];
    f16x8 aq1 = *(const f16x8*)&sQh[(wn * 32 + 16 + r) * 72 + kk + q * 8];
#pragma unroll
    for (int j = 0; j < 4; ++j) {
      f16x8 bk8 = *(const f16x8*)&sKh[(j * 16 + r) * 72 + kk + q * 8];
      s2[0][j] = __builtin_amdgcn_mfma_f32_16x16x32_f16(aq0, bk8, s2[0][j], 0, 0, 0);
      s2[1][j] = __builtin_amdgcn_mfma_f32_16x16x32_f16(aq1, bk8, s2[1][j], 0, 0, 0);
    }
  }
  // softmax over w' (no scale in reference); lane holds S[row][col=j*16+r]
  float inv2[2][4];
#pragma unroll
  for (int i2 = 0; i2 < 2; ++i2)
#pragma unroll
    for (int reg = 0; reg < 4; ++reg) {
      float mx = fmaxf(fmaxf(s2[i2][0][reg], s2[i2][1][reg]),
                       fmaxf(s2[i2][2][reg], s2[i2][3][reg]));
#pragma unroll
      for (int o = 1; o < 16; o <<= 1) mx = fmaxf(mx, __shfl_xor(mx, o, 64));
      float p0 = __expf(s2[i2][0][reg] - mx);
      float p1 = __expf(s2[i2][1][reg] - mx);
      float p2 = __expf(s2[i2][2][reg] - mx);
      float p3 = __expf(s2[i2][3][reg] - mx);
      float sum = p0 + p1 + p2 + p3;
#pragma unroll
      for (int o = 1; o < 16; o <<= 1) sum += __shfl_xor(sum, o, 64);
      inv2[i2][reg] = 1.0f / sum;
      const int row = wn * 32 + i2 * 16 + q * 4 + reg;
      sPh[row * 72 + r] = f2h(p0);
      sPh[row * 72 + 16 + r] = f2h(p1);
      sPh[row * 72 + 32 + r] = f2h(p2);
      sPh[row * 72 + 48 + r] = f2h(p3);
    }
  __syncthreads();  // QK reads done before sO overlays sQ/sK; sP visible
  f32x4 o4[2][4];
#pragma unroll
  for (int i2 = 0; i2 < 2; ++i2)
#pragma unroll
    for (int jd = 0; jd < 4; ++jd) o4[i2][jd] = (f32x4){0.f, 0.f, 0.f, 0.f};
#pragma unroll
  for (int kk = 0; kk < 64; kk += 32) {
    f16x8 ap0 = *(const f16x8*)&sPh[(wn * 32 + r) * 72 + kk + q * 8];
    f16x8 ap1 = *(const f16x8*)&sPh[(wn * 32 + 16 + r) * 72 + kk + q * 8];
#pragma unroll
    for (int jd = 0; jd < 4; ++jd) {
      f16x8 bv8 = *(const f16x8*)&sVh[(jd * 16 + r) * 72 + kk + q * 8];
      o4[0][jd] = __builtin_amdgcn_mfma_f32_16x16x32_f16(ap0, bv8, o4[0][jd], 0, 0, 0);
      o4[1][jd] = __builtin_amdgcn_mfma_f32_16x16x32_f16(ap1, bv8, o4[1][jd], 0, 0, 0);
    }
  }
  float* sOh = (float*)(smem + wm * 27648);  // [64 d][66 w], overlays sQ[hs]+sK[hs]
#pragma unroll
  for (int i2 = 0; i2 < 2; ++i2)
#pragma unroll
    for (int jd = 0; jd < 4; ++jd) {
      const int d = jd * 16 + r;
#pragma unroll
      for (int reg = 0; reg < 4; ++reg) {
        const int w = wn * 32 + i2 * 16 + q * 4 + reg;
        sOh[d * 66 + w] = o4[i2][jd][reg] * inv2[i2][reg];
      }
    }
  __syncthreads();
  // out[b][head*64+d][h][w] = O[w][d] + x; coalesced float4 along w, both h-rows
  const int d = t >> 2, w0 = (t & 3) * 16;
#pragma unroll
  for (int hs = 0; hs < 2; ++hs) {
    const float* sO2 = (const float*)(smem + hs * 27648);
    const int h = ht * 2 + hs;
    const size_t obase = (((size_t)b * C_ + head * 64 + d) * H_ + h) * (size_t)W_ + w0;
    const float4* xr = (const float4*)(x + obase);
    float4* op = (float4*)(out + obase);
#pragma unroll
    for (int u = 0; u < 4; ++u) {
      float4 xv = xr[u];
      float4 ov;
      ov.x = sO2[d * 66 + w0 + u * 4 + 0] + xv.x;
      ov.y = sO2[d * 66 + w0 + u * 4 + 1] + xv.y;
      ov.z = sO2[d * 66 + w0 + u * 4 + 2] + xv.z;
      ov.w = sO2[d * 66 + w0 + u * 4 + 3] + xv.w;
      op[u] = ov;
    }
  }
}

extern "C" void kernel_launch(void* const* d_in, const int* in_sizes, int n_in,
                              void* d_out, int out_size, void* d_ws, size_t ws_size,
                              hipStream_t stream) {
  const float* x  = (const float*)d_in[0];
  const float* wq = (const float*)d_in[1];
  const float* bq = (const float*)d_in[2];
  const float* wk = (const float*)d_in[3];
  const float* bk = (const float*)d_in[4];
  const float* wv = (const float*)d_in[5];
  const float* bv = (const float*)d_in[6];
  float* out = (float*)d_out;
  char* ws = (char*)d_ws;
  // ws layout: xT 64 MiB | Wc 1.5 MiB
  unsigned short* xT = (unsigned short*)ws;
  unsigned short* Wc = (unsigned short*)(ws + (size_t)67108864);
  hipLaunchKernelGGL(rcca_tr,    dim3(8192), dim3(256), 0, stream, x, xT);
  hipLaunchKernelGGL(rcca_cvtw,  dim3(768),  dim3(256), 0, stream, wq, wk, wv, Wc);
  hipLaunchKernelGGL(rcca_fused, dim3(4096), dim3(256), 0, stream, xT, Wc, bq, bk, bv, x, out);
}